// Round 7
// baseline (159.733 us; speedup 1.0000x reference)
//
#include <hip/hip_runtime.h>

#define NTAG 64
#define TLEN 512
#define START_TAG 62
#define STOP_TAG 63
#define NB 16            // batch columns per tile (one fwd wave + one bwd wave)

typedef __attribute__((ext_vector_type(4))) float    f32x4;
typedef __attribute__((ext_vector_type(8))) short    s16x8;
typedef __attribute__((ext_vector_type(2))) unsigned u32x2;
typedef __attribute__((ext_vector_type(4))) unsigned u32x4;

#if __has_builtin(__builtin_amdgcn_exp2f)
#define EXP2(x) __builtin_amdgcn_exp2f(x)
#else
#define EXP2(x) exp2f(x)
#endif

// v_cvt_pk_bf16_f32: D.lo = bf16(S0), D.hi = bf16(S1)
__device__ __forceinline__ unsigned cvtpk_bf16(float lo, float hi) {
    unsigned r;
    asm("v_cvt_pk_bf16_f32 %0, %1, %2" : "=v"(r) : "v"(lo), "v"(hi));
    return r;
}

// gfx950-verified builtin (m89/m92/m97). C/D: col=lane&15, row=4*(lane>>4)+reg.
__device__ __forceinline__ f32x4 mfma32(s16x8 a, s16x8 b, f32x4 c) {
    return __builtin_amdgcn_mfma_f32_16x16x32_bf16(a, b, c, 0, 0, 0);
}

// ROUND-7: revert to the round-3-VERIFIED skeleton (2 waves, pure-register
// MFMA recursion, register prefetch ring, no producer waves, no LDS staging).
// Rounds 4/5/6 NaN'd with the 6-wave producer structure even under a provably
// stable renorm -> that machinery is abandoned, not debugged further.
//
// Deltas vs round 3 (all inside the verified skeleton):
//  1. pe = exp2(emis*L2E) precomputed ONE STEP AHEAD from the prefetch ring
//     (double-buffered peA/peB) -> the 16 quarter-rate v_exp leave the
//     loop-carried chain. Rescale is a separate exact-pow2 multiply.
//  2. Renorm: period-2 lag-2 FULL apply. Measure colmax at even steps, apply
//     at t+2, apply 0 at odd steps. M_even = g_{t-1}+g_t (pure FIR, NO
//     feedback -> unconditionally stable, |M| <= ~45 bits worst-case);
//     2 steps of slack hides the shuffle latency. off stays exact.
//  3. Prefetch ring depth 8 (~1100cy lookahead).
__global__ __launch_bounds__(128) void crf_fwd_bwd(
    const float* __restrict__ emis,   // [512, 512, 64] f32
    const float* __restrict__ trans,  // [64, 64] f32, trans[next, prev]
    float* __restrict__ out)          // [512] f32
{
    const int tile = blockIdx.x;
    const int tid  = threadIdx.x;
    const int lane = tid & 63;
    const int w    = tid >> 6;      // 0 = fwd (t=0..255), 1 = bwd (t=511..256)
    const int c    = lane & 15;     // batch column within tile
    const int g    = lane >> 4;     // 4-row group
    const int b0   = tile * NB;

    const float L2E = 1.4426950408889634f;
    const float LN2 = 0.6931471805599453f;

    __shared__ float fy[64][17];    // bwd final beta (f32), +1 pad col
    __shared__ int   offb_sh[16];   // bwd pow2 offset per column

    // A fragments with baked rho-permutation (round-3-verified).
    s16x8 Af[4][2];
    #pragma unroll
    for (int m = 0; m < 4; ++m) {
        #pragma unroll
        for (int kt = 0; kt < 2; ++kt) {
            float ev[8];
            #pragma unroll
            for (int jj = 0; jj < 8; ++jj) {
                const int r = 16 * m + c;
                const int k = 32 * kt + 16 * (jj >> 2) + 4 * g + (jj & 3);
                const float tv = (w == 0) ? trans[r * NTAG + k]
                                          : trans[k * NTAG + r];
                ev[jj] = EXP2(tv * L2E);   // masked (-10000) -> exactly 0
            }
            u32x4 p;
            p[0] = cvtpk_bf16(ev[0], ev[1]);
            p[1] = cvtpk_bf16(ev[2], ev[3]);
            p[2] = cvtpk_bf16(ev[4], ev[5]);
            p[3] = cvtpk_bf16(ev[6], ev[7]);
            Af[m][kt] = __builtin_bit_cast(s16x8, p);
        }
    }

    // lane (g,c) owns rows 16m+4g+{0..3} of batch column c.
    const float* ebase = emis + (size_t)(b0 + c) * (TLEN * NTAG) + 4 * g;

    f32x4 wq[8][4];          // depth-8 emission prefetch ring (raw scores)
    f32x4 peA[4], peB[4];    // pre-exponentiated weights, even/odd steps
    u32x2 Bf[4];             // state: 4 packed bf16 B-fragments (8 VGPRs)
    f32x4 ym[4];             // current step f32 outputs
    int   off = 0;           // accumulated pow2 offset (exact)
    int   erA = 0, erB = 0;  // alternating colmax-exponent registers

    #define PREF_F(slot, t) do {                                       \
        const float* _p = ebase + (t) * NTAG;                          \
        wq[slot][0] = *(const f32x4*)(_p +  0);                        \
        wq[slot][1] = *(const f32x4*)(_p + 16);                        \
        wq[slot][2] = *(const f32x4*)(_p + 32);                        \
        wq[slot][3] = *(const f32x4*)(_p + 48);                        \
    } while (0)
    #define PREF_B(slot, tp) PREF_F(slot, 510 - (tp))

    #define EXPQ(dst, slot) do {                                       \
        _Pragma("unroll")                                              \
        for (int m_ = 0; m_ < 4; ++m_) {                               \
            dst[m_][0] = EXP2(wq[slot][m_][0] * L2E);                  \
            dst[m_][1] = EXP2(wq[slot][m_][1] * L2E);                  \
            dst[m_][2] = EXP2(wq[slot][m_][2] * L2E);                  \
            dst[m_][3] = EXP2(wq[slot][m_][3] * L2E);                  \
        }                                                              \
    } while (0)

    #define BCAT(i) __builtin_bit_cast(s16x8,                          \
        (u32x4){Bf[2*(i)].x, Bf[2*(i)].y, Bf[2*(i)+1].x, Bf[2*(i)+1].y})

    #define MFMA_ALL() do {                                            \
        s16x8 B0_ = BCAT(0), B1_ = BCAT(1);                            \
        f32x4 a0 = {0.f,0.f,0.f,0.f}, a1 = a0, a2 = a0, a3 = a0;       \
        a0 = mfma32(Af[0][0], B0_, a0); a1 = mfma32(Af[1][0], B0_, a1);\
        a2 = mfma32(Af[2][0], B0_, a2); a3 = mfma32(Af[3][0], B0_, a3);\
        a0 = mfma32(Af[0][1], B1_, a0); a1 = mfma32(Af[1][1], B1_, a1);\
        a2 = mfma32(Af[2][1], B1_, a2); a3 = mfma32(Af[3][1], B1_, a3);\
        ym[0] = a0; ym[1] = a1; ym[2] = a2; ym[3] = a3;                \
    } while (0)

    #define PACK() do {                                                \
        Bf[0].x = cvtpk_bf16(ym[0][0], ym[0][1]);                      \
        Bf[0].y = cvtpk_bf16(ym[0][2], ym[0][3]);                      \
        Bf[1].x = cvtpk_bf16(ym[1][0], ym[1][1]);                      \
        Bf[1].y = cvtpk_bf16(ym[1][2], ym[1][3]);                      \
        Bf[2].x = cvtpk_bf16(ym[2][0], ym[2][1]);                      \
        Bf[2].y = cvtpk_bf16(ym[2][2], ym[2][3]);                      \
        Bf[3].x = cvtpk_bf16(ym[3][0], ym[3][1]);                      \
        Bf[3].y = cvtpk_bf16(ym[3][2], ym[3][3]);                      \
    } while (0)

    // Column max over {lane, lane^16, lane^32, lane^48} (closed group ->
    // 3 independent shuffles, latencies overlap). Guard zero / inf-nan.
    #define COLMAX_TO(dst, mxv) do {                                   \
        float _m = (mxv);                                              \
        const float _s1 = __shfl_xor(_m, 16, 64);                      \
        const float _s2 = __shfl_xor(_m, 32, 64);                      \
        const float _s3 = __shfl_xor(_m, 48, 64);                      \
        _m = fmaxf(fmaxf(_m, _s1), fmaxf(_s2, _s3));                   \
        const int _ef = (int)((__float_as_uint(_m) >> 23) & 0xffu);    \
        dst = (_ef == 0 || _ef == 0xff) ? 0 : _ef - 127;               \
    } while (0)

    // Even step: apply ERAPP (exact pow2), measure colmax into ERMEAS.
    #define CSTEP_E(u, PEC, PEN, ERAPP, ERMEAS, PRFM, tb) do {         \
        off += ERAPP;                                                  \
        const float rs_ =                                              \
            __uint_as_float((unsigned)(127 - (ERAPP)) << 23);          \
        MFMA_ALL();                                                    \
        EXPQ(PEN, ((u) + 1) & 7);                                     \
        ym[0] = ym[0] * PEC[0] * rs_; ym[1] = ym[1] * PEC[1] * rs_;    \
        ym[2] = ym[2] * PEC[2] * rs_; ym[3] = ym[3] * PEC[3] * rs_;    \
        PACK();                                                        \
        float mx_ = fmaxf(fmaxf(fmaxf(ym[0][0], ym[0][1]),             \
                                fmaxf(ym[0][2], ym[0][3])),            \
                          fmaxf(fmaxf(ym[1][0], ym[1][1]),             \
                                fmaxf(ym[1][2], ym[1][3])));           \
        mx_ = fmaxf(mx_, fmaxf(fmaxf(ym[2][0], ym[2][1]),              \
                               fmaxf(ym[2][2], ym[2][3])));            \
        mx_ = fmaxf(mx_, fmaxf(fmaxf(ym[3][0], ym[3][1]),              \
                               fmaxf(ym[3][2], ym[3][3])));            \
        COLMAX_TO(ERMEAS, mx_);                                        \
        PRFM((u), (tb) + (u) + 8);                                     \
    } while (0)

    // Odd step: no renorm, no measurement.
    #define CSTEP_O(u, PEC, PEN, PRFM, tb) do {                        \
        MFMA_ALL();                                                    \
        EXPQ(PEN, ((u) + 1) & 7);                                     \
        ym[0] *= PEC[0]; ym[1] *= PEC[1];                              \
        ym[2] *= PEC[2]; ym[3] *= PEC[3];                              \
        PACK();                                                        \
        PRFM((u), (tb) + (u) + 8);                                     \
    } while (0)

    #define OCTET(PRFM, tb)                                            \
        CSTEP_E(0, peA, peB, erB, erA, PRFM, tb);                      \
        CSTEP_O(1, peB, peA, PRFM, tb);                                \
        CSTEP_E(2, peA, peB, erA, erB, PRFM, tb);                      \
        CSTEP_O(3, peB, peA, PRFM, tb);                                \
        CSTEP_E(4, peA, peB, erB, erA, PRFM, tb);                      \
        CSTEP_O(5, peB, peA, PRFM, tb);                                \
        CSTEP_E(6, peA, peB, erA, erB, PRFM, tb);                      \
        CSTEP_O(7, peB, peA, PRFM, tb);

    if (w == 0) {
        // ============================ FORWARD =============================
        // seed alpha_0 = indicator(START=62): row 62 -> Bf[3].y low half
        Bf[0].x = 0u; Bf[0].y = 0u; Bf[1] = Bf[0]; Bf[2] = Bf[0];
        Bf[3].x = 0u; Bf[3].y = (g == 3) ? 0x3f80u : 0u;
        erA = 0; erB = 0;   // seed max = 1.0 exactly

        PREF_F(0, 0); PREF_F(1, 1); PREF_F(2, 2); PREF_F(3, 3);
        PREF_F(4, 4); PREF_F(5, 5); PREF_F(6, 6); PREF_F(7, 7);
        EXPQ(peA, 0);       // pe for t=0

        #pragma clang loop unroll(disable)
        for (int it = 0; it < 32; ++it) {
            const int tb = it * 8;
            OCTET(PREF_F, tb)        // t = tb..tb+7 (overrun loads <= t=263, in-bounds)
        }
        // ym = alpha_255 * 2^-off (f32)
    } else {
        // ============================ BACKWARD ============================
        // seed z_511[r][c] = exp(trans[STOP][r] + emis[c][511][r])
        float smx = 0.f;
        #pragma unroll
        for (int m = 0; m < 4; ++m) {
            f32x4 wv = *(const f32x4*)(ebase + 511 * NTAG + 16 * m);
            float v[4];
            #pragma unroll
            for (int j = 0; j < 4; ++j) {
                const int r = 16 * m + 4 * g + j;
                v[j] = EXP2((trans[STOP_TAG * NTAG + r] + wv[j]) * L2E);
                smx = fmaxf(smx, v[j]);
            }
            Bf[m].x = cvtpk_bf16(v[0], v[1]);
            Bf[m].y = cvtpk_bf16(v[2], v[3]);
        }
        COLMAX_TO(erB, smx);   // applied at t'=0 (full, immediate window)
        erA = 0;

        PREF_B(0, 0); PREF_B(1, 1); PREF_B(2, 2); PREF_B(3, 3);
        PREF_B(4, 4); PREF_B(5, 5); PREF_B(6, 6); PREF_B(7, 7);
        EXPQ(peA, 0);          // pe for t'=0 (t=510)

        #pragma clang loop unroll(disable)
        for (int it = 0; it < 31; ++it) {
            const int tb = it * 8;
            OCTET(PREF_B, tb)        // t' = tb..tb+7
        }
        // tail t' = 248..254 (7 steps; overrun loads t'<=262 -> t>=248, valid)
        {
            const int tb = 248;
            CSTEP_E(0, peA, peB, erB, erA, PREF_B, tb);
            CSTEP_O(1, peB, peA, PREF_B, tb);
            CSTEP_E(2, peA, peB, erA, erB, PREF_B, tb);
            CSTEP_O(3, peB, peA, PREF_B, tb);
            CSTEP_E(4, peA, peB, erB, erA, PREF_B, tb);
            CSTEP_O(5, peB, peA, PREF_B, tb);
            CSTEP_E(6, peA, peB, erA, erB, PREF_B, tb);  // measures erB=m(254)
        }
        // bare matvec: beta = E^T z_256, apply pending erB (lag-2 slot t'=256)
        off += erB;
        const float rs = __uint_as_float((unsigned)(127 - erB) << 23);
        MFMA_ALL();
        ym[0] *= rs; ym[1] *= rs; ym[2] *= rs; ym[3] *= rs;

        #pragma unroll
        for (int m = 0; m < 4; ++m)
            #pragma unroll
            for (int j = 0; j < 4; ++j)
                fy[lane][4 * m + j] = ym[m][j];
        if (lane < 16) offb_sh[lane] = off;
    }

    __syncthreads();

    if (w == 0) {
        // logZ_c = ln2 * ( log2( sum_r alpha[r][c]*beta[r][c] ) + off_f + off_b )
        float p = 0.f;
        #pragma unroll
        for (int m = 0; m < 4; ++m)
            #pragma unroll
            for (int j = 0; j < 4; ++j)
                p = fmaf(ym[m][j], fy[lane][4 * m + j], p);
        p += __shfl_xor(p, 16, 64);
        p += __shfl_xor(p, 32, 64);
        if (lane < 16)
            out[b0 + lane] = LN2 * (log2f(p) + (float)(off + offb_sh[lane]));
    }

    #undef PREF_F
    #undef PREF_B
    #undef EXPQ
    #undef BCAT
    #undef MFMA_ALL
    #undef PACK
    #undef COLMAX_TO
    #undef CSTEP_E
    #undef CSTEP_O
    #undef OCTET
}

extern "C" void kernel_launch(void* const* d_in, const int* in_sizes, int n_in,
                              void* d_out, int out_size, void* d_ws, size_t ws_size,
                              hipStream_t stream) {
    const float* emis  = (const float*)d_in[0];   // [512, 512, 64] f32
    const float* trans = (const float*)d_in[1];   // [64, 64] f32
    float* out = (float*)d_out;                   // [512] f32
    (void)in_sizes; (void)n_in; (void)out_size; (void)d_ws; (void)ws_size;
    crf_fwd_bwd<<<512 / NB, 128, 0, stream>>>(emis, trans, out);
}